// Round 1
// baseline (467.973 us; speedup 1.0000x reference)
//
#include <hip/hip_runtime.h>
#include <hip/hip_bf16.h>

// Cone-beam backprojection, TIGRE-style geometry.
// sinogram: [B=1, C=8, A=120, V=128, U=128] f32
// angles:   [A=120] f32
// out:      [B=1, C=8, NZ=96, NY=96, NX=96] f32

#define A_N   120
#define V_N   128
#define U_N   128
#define NZv   96
#define NYv   96
#define NXv   96
#define C_N   8

constexpr float DSO  = 1000.0f;
constexpr float DSD  = 1500.0f;
constexpr float DVOX = 0.8f;
// DU = DV = 1.0

#define NVOX (NZv * NYv * NXv)          // 884736
#define SINO_N (A_N * V_N * U_N)        // 1966080 per channel

// ---------------------------------------------------------------------------
// Pre-pass: [C, A, V, U] -> [A, V, U, C]  (channels innermost, 32 B groups)
// ---------------------------------------------------------------------------
__global__ __launch_bounds__(256) void sino_transpose(
    const float* __restrict__ in, float* __restrict__ out) {
  int idx = blockIdx.x * 256 + threadIdx.x;   // over A*V*U, exact grid
  float v[C_N];
#pragma unroll
  for (int c = 0; c < C_N; ++c) v[c] = in[(size_t)c * SINO_N + idx];
  float* o = out + (size_t)idx * C_N;
#pragma unroll
  for (int c = 0; c < C_N; ++c) o[c] = v[c];
}

// ---------------------------------------------------------------------------
// Backprojection, transposed sinogram layout [A][V][U][C]
// ---------------------------------------------------------------------------
__global__ __launch_bounds__(256) void backproject_t(
    const float* __restrict__ sino,     // [A][V][U][C]
    const float* __restrict__ angles,
    float* __restrict__ out) {
  __shared__ float s_cos[A_N];
  __shared__ float s_sin[A_N];
  int tid = threadIdx.x;
  if (tid < A_N) {
    float a = angles[tid];
    s_cos[tid] = cosf(a);
    s_sin[tid] = sinf(a);
  }
  __syncthreads();

  int vi = blockIdx.x * 256 + tid;            // exact grid, no bounds check
  int x = vi % NXv;
  int t = vi / NXv;
  int y = t % NYv;
  int z = t / NYv;

  float xf = ((float)x - (NXv - 1) * 0.5f) * DVOX;
  float yf = ((float)y - (NYv - 1) * 0.5f) * DVOX;
  float zf = ((float)z - (NZv - 1) * 0.5f) * DVOX;

  float acc[C_N];
#pragma unroll
  for (int c = 0; c < C_N; ++c) acc[c] = 0.0f;

  for (int a = 0; a < A_N; ++a) {
    float cs = s_cos[a], sn = s_sin[a];
    float xr = xf * cs + yf * sn;
    float yr = -xf * sn + yf * cs;
    float mag = DSD / (DSO - xr);
    float iu = yr * mag + (U_N - 1) * 0.5f;
    float iv = zf * mag + (V_N - 1) * 0.5f;
    if (iu < 0.0f || iu > (float)(U_N - 1) || iv < 0.0f || iv > (float)(V_N - 1))
      continue;
    float u0f = floorf(iu), v0f = floorf(iv);
    float fu = iu - u0f, fv = iv - v0f;
    int u0 = (int)u0f, v0 = (int)v0f;           // in range by validity check
    int u1 = min(u0 + 1, U_N - 1);
    int v1 = min(v0 + 1, V_N - 1);
    float w = mag * mag;
    float w00 = w * (1.0f - fv) * (1.0f - fu);
    float w01 = w * (1.0f - fv) * fu;
    float w10 = w * fv * (1.0f - fu);
    float w11 = w * fv * fu;

    const float* p00 = sino + ((size_t)((a * V_N + v0) * U_N + u0)) * C_N;
    const float* p01 = sino + ((size_t)((a * V_N + v0) * U_N + u1)) * C_N;
    const float* p10 = sino + ((size_t)((a * V_N + v1) * U_N + u0)) * C_N;
    const float* p11 = sino + ((size_t)((a * V_N + v1) * U_N + u1)) * C_N;
#pragma unroll
    for (int c = 0; c < C_N; ++c)
      acc[c] += w00 * p00[c] + w01 * p01[c] + w10 * p10[c] + w11 * p11[c];
  }

#pragma unroll
  for (int c = 0; c < C_N; ++c)
    out[(size_t)c * NVOX + vi] = acc[c];
}

// ---------------------------------------------------------------------------
// Fallback: direct [C][A][V][U] layout (if workspace too small for transpose)
// ---------------------------------------------------------------------------
__global__ __launch_bounds__(256) void backproject_direct(
    const float* __restrict__ sino,     // [C][A][V][U]
    const float* __restrict__ angles,
    float* __restrict__ out) {
  __shared__ float s_cos[A_N];
  __shared__ float s_sin[A_N];
  int tid = threadIdx.x;
  if (tid < A_N) {
    float a = angles[tid];
    s_cos[tid] = cosf(a);
    s_sin[tid] = sinf(a);
  }
  __syncthreads();

  int vi = blockIdx.x * 256 + tid;
  int x = vi % NXv;
  int t = vi / NXv;
  int y = t % NYv;
  int z = t / NYv;

  float xf = ((float)x - (NXv - 1) * 0.5f) * DVOX;
  float yf = ((float)y - (NYv - 1) * 0.5f) * DVOX;
  float zf = ((float)z - (NZv - 1) * 0.5f) * DVOX;

  float acc[C_N];
#pragma unroll
  for (int c = 0; c < C_N; ++c) acc[c] = 0.0f;

  for (int a = 0; a < A_N; ++a) {
    float cs = s_cos[a], sn = s_sin[a];
    float xr = xf * cs + yf * sn;
    float yr = -xf * sn + yf * cs;
    float mag = DSD / (DSO - xr);
    float iu = yr * mag + (U_N - 1) * 0.5f;
    float iv = zf * mag + (V_N - 1) * 0.5f;
    if (iu < 0.0f || iu > (float)(U_N - 1) || iv < 0.0f || iv > (float)(V_N - 1))
      continue;
    float u0f = floorf(iu), v0f = floorf(iv);
    float fu = iu - u0f, fv = iv - v0f;
    int u0 = (int)u0f, v0 = (int)v0f;
    int u1 = min(u0 + 1, U_N - 1);
    int v1 = min(v0 + 1, V_N - 1);
    float w = mag * mag;
    float w00 = w * (1.0f - fv) * (1.0f - fu);
    float w01 = w * (1.0f - fv) * fu;
    float w10 = w * fv * (1.0f - fu);
    float w11 = w * fv * fu;

    int b00 = (a * V_N + v0) * U_N + u0;
    int b01 = (a * V_N + v0) * U_N + u1;
    int b10 = (a * V_N + v1) * U_N + u0;
    int b11 = (a * V_N + v1) * U_N + u1;
#pragma unroll
    for (int c = 0; c < C_N; ++c) {
      const float* pc = sino + (size_t)c * SINO_N;
      acc[c] += w00 * pc[b00] + w01 * pc[b01] + w10 * pc[b10] + w11 * pc[b11];
    }
  }

#pragma unroll
  for (int c = 0; c < C_N; ++c)
    out[(size_t)c * NVOX + vi] = acc[c];
}

extern "C" void kernel_launch(void* const* d_in, const int* in_sizes, int n_in,
                              void* d_out, int out_size, void* d_ws, size_t ws_size,
                              hipStream_t stream) {
  const float* sino   = (const float*)d_in[0];
  const float* angles = (const float*)d_in[1];
  float* out = (float*)d_out;

  size_t need = (size_t)C_N * SINO_N * sizeof(float);   // 62.9 MB
  if (ws_size >= need) {
    float* sino_t = (float*)d_ws;
    sino_transpose<<<SINO_N / 256, 256, 0, stream>>>(sino, sino_t);
    backproject_t<<<NVOX / 256, 256, 0, stream>>>(sino_t, angles, out);
  } else {
    backproject_direct<<<NVOX / 256, 256, 0, stream>>>(sino, angles, out);
  }
}

// Round 3
// 283.747 us; speedup vs baseline: 1.6493x; 1.6493x over previous
//
#include <hip/hip_runtime.h>
#include <hip/hip_fp16.h>

// Cone-beam backprojection, TIGRE-style geometry.
// sinogram: [B=1, C=8, A=120, V=128, U=128] f32
// angles:   [A=120] f32
// out:      [B=1, C=8, NZ=96, NY=96, NX=96] f32
//
// Strategy: pre-pass converts sinogram to f16 in [A][V][U][C] layout so one
// bilinear corner for all 8 channels is a single 16B load. Main kernel:
// thread = (x, y, z-pair); geometry + u-interp setup shared across the pair;
// packed __half2 corner math; f32 accumulation across angles; branchless.

#define A_N   120
#define V_N   128
#define U_N   128
#define NZv   96
#define NYv   96
#define NXv   96
#define C_N   8

constexpr float DSO  = 1000.0f;
constexpr float DSD  = 1500.0f;
constexpr float DVOX = 0.8f;

#define NVOX   (NZv * NYv * NXv)        // 884736
#define SINO_N (A_N * V_N * U_N)        // 1966080 per channel

struct alignas(16) H8 { __half2 h[4]; };   // 8 channels as 4x half2 = 16 B

// ---------------------------------------------------------------------------
// Pre-pass: [C, A, V, U] f32 -> [A, V, U, C] f16 (one 16B record per (a,v,u))
// ---------------------------------------------------------------------------
__global__ __launch_bounds__(256) void sino_to_h(
    const float* __restrict__ in, H8* __restrict__ out) {
  int idx = blockIdx.x * 256 + threadIdx.x;   // over A*V*U, exact grid
  H8 o;
#pragma unroll
  for (int i = 0; i < 4; ++i) {
    float lo = in[(size_t)(2 * i)     * SINO_N + idx];
    float hi = in[(size_t)(2 * i + 1) * SINO_N + idx];
    o.h[i] = __floats2half2_rn(lo, hi);
  }
  out[idx] = o;
}

// ---------------------------------------------------------------------------
// Backprojection, f16 [A][V][U][C] layout, z-pair per thread
// ---------------------------------------------------------------------------
__global__ __launch_bounds__(256) void backproject_h(
    const H8* __restrict__ sino,
    const float* __restrict__ angles,
    float* __restrict__ out) {
  __shared__ float s_c[A_N];
  __shared__ float s_s[A_N];
  int tid = threadIdx.x;
  if (tid < A_N) {
    float a = angles[tid];
    s_c[tid] = cosf(a);
    s_s[tid] = sinf(a);
  }
  __syncthreads();

  int t = blockIdx.x * 256 + tid;            // over NVOX/2, exact grid
  int x  = t % NXv;
  int r  = t / NXv;
  int y  = r % NYv;
  int z0 = (r / NYv) * 2;

  float xf  = ((float)x  - (NXv - 1) * 0.5f) * DVOX;
  float yf  = ((float)y  - (NYv - 1) * 0.5f) * DVOX;
  float zf0 = ((float)z0 - (NZv - 1) * 0.5f) * DVOX;
  float zf1 = zf0 + DVOX;

  float2 acc0[4], acc1[4];
#pragma unroll
  for (int i = 0; i < 4; ++i) {
    acc0[i] = make_float2(0.0f, 0.0f);
    acc1[i] = make_float2(0.0f, 0.0f);
  }

  for (int a = 0; a < A_N; ++a) {
    float cs = s_c[a], sn = s_s[a];
    float xr  = xf * cs + yf * sn;
    float yr  = yf * cs - xf * sn;
    float mag = DSD / (DSO - xr);
    float w   = mag * mag;

    // u-interp setup shared by both z's
    float iu  = yr * mag + (U_N - 1) * 0.5f;
    bool uok  = (iu >= 0.0f) && (iu <= (float)(U_N - 1));
    float iuc = fminf(fmaxf(iu, 0.0f), (float)(U_N - 1));
    float u0f = floorf(iuc);
    float fu  = iuc - u0f;
    float gu0 = 1.0f - fu;
    int u0 = (int)u0f;
    int u1 = min(u0 + 1, U_N - 1);
    int base = a * (V_N * U_N);
    int b0 = base + u0;                      // record index, 32-bit
    int b1 = base + u1;

#pragma unroll
    for (int zz = 0; zz < 2; ++zz) {
      float  zf  = zz ? zf1  : zf0;
      float2* acc = zz ? acc1 : acc0;

      float iv  = zf * mag + (V_N - 1) * 0.5f;
      bool ok   = uok && (iv >= 0.0f) && (iv <= (float)(V_N - 1));
      float ivc = fminf(fmaxf(iv, 0.0f), (float)(V_N - 1));
      float v0f = floorf(ivc);
      float fv  = ivc - v0f;
      int v0 = (int)v0f;
      int v1 = min(v0 + 1, V_N - 1);
      float wz  = ok ? w : 0.0f;             // branchless validity
      float wv0 = wz * (1.0f - fv);
      float wv1 = wz * fv;

      __half2 h00 = __float2half2_rn(wv0 * gu0);
      __half2 h01 = __float2half2_rn(wv0 * fu);
      __half2 h10 = __float2half2_rn(wv1 * gu0);
      __half2 h11 = __float2half2_rn(wv1 * fu);

      H8 c00 = sino[b0 + v0 * U_N];
      H8 c01 = sino[b1 + v0 * U_N];
      H8 c10 = sino[b0 + v1 * U_N];
      H8 c11 = sino[b1 + v1 * U_N];

#pragma unroll
      for (int i = 0; i < 4; ++i) {
        __half2 s = __hfma2(c00.h[i], h00,
                    __hfma2(c01.h[i], h01,
                    __hfma2(c10.h[i], h10,
                    __hmul2(c11.h[i], h11))));
        float2 sf = __half22float2(s);
        acc[i].x += sf.x;
        acc[i].y += sf.y;
      }
    }
  }

  int vi0 = (z0 * NYv + y) * NXv + x;
  int vi1 = vi0 + NYv * NXv;
#pragma unroll
  for (int i = 0; i < 4; ++i) {
    out[(size_t)(2 * i)     * NVOX + vi0] = acc0[i].x;
    out[(size_t)(2 * i + 1) * NVOX + vi0] = acc0[i].y;
    out[(size_t)(2 * i)     * NVOX + vi1] = acc1[i].x;
    out[(size_t)(2 * i + 1) * NVOX + vi1] = acc1[i].y;
  }
}

// ---------------------------------------------------------------------------
// Fallback: direct [C][A][V][U] f32 layout (if workspace too small)
// ---------------------------------------------------------------------------
__global__ __launch_bounds__(256) void backproject_direct(
    const float* __restrict__ sino,
    const float* __restrict__ angles,
    float* __restrict__ out) {
  __shared__ float s_c[A_N];
  __shared__ float s_s[A_N];
  int tid = threadIdx.x;
  if (tid < A_N) {
    float a = angles[tid];
    s_c[tid] = cosf(a);
    s_s[tid] = sinf(a);
  }
  __syncthreads();

  int vi = blockIdx.x * 256 + tid;
  int x = vi % NXv;
  int t = vi / NXv;
  int y = t % NYv;
  int z = t / NYv;

  float xf = ((float)x - (NXv - 1) * 0.5f) * DVOX;
  float yf = ((float)y - (NYv - 1) * 0.5f) * DVOX;
  float zf = ((float)z - (NZv - 1) * 0.5f) * DVOX;

  float acc[C_N];
#pragma unroll
  for (int c = 0; c < C_N; ++c) acc[c] = 0.0f;

  for (int a = 0; a < A_N; ++a) {
    float cs = s_c[a], sn = s_s[a];
    float xr = xf * cs + yf * sn;
    float yr = yf * cs - xf * sn;
    float mag = DSD / (DSO - xr);
    float iu = yr * mag + (U_N - 1) * 0.5f;
    float iv = zf * mag + (V_N - 1) * 0.5f;
    if (iu < 0.0f || iu > (float)(U_N - 1) || iv < 0.0f || iv > (float)(V_N - 1))
      continue;
    float u0f = floorf(iu), v0f = floorf(iv);
    float fu = iu - u0f, fv = iv - v0f;
    int u0 = (int)u0f, v0 = (int)v0f;
    int u1 = min(u0 + 1, U_N - 1);
    int v1 = min(v0 + 1, V_N - 1);
    float w = mag * mag;
    float w00 = w * (1.0f - fv) * (1.0f - fu);
    float w01 = w * (1.0f - fv) * fu;
    float w10 = w * fv * (1.0f - fu);
    float w11 = w * fv * fu;

    int b00 = (a * V_N + v0) * U_N + u0;
    int b01 = (a * V_N + v0) * U_N + u1;
    int b10 = (a * V_N + v1) * U_N + u0;
    int b11 = (a * V_N + v1) * U_N + u1;
#pragma unroll
    for (int c = 0; c < C_N; ++c) {
      const float* pc = sino + (size_t)c * SINO_N;
      acc[c] += w00 * pc[b00] + w01 * pc[b01] + w10 * pc[b10] + w11 * pc[b11];
    }
  }

#pragma unroll
  for (int c = 0; c < C_N; ++c)
    out[(size_t)c * NVOX + vi] = acc[c];
}

extern "C" void kernel_launch(void* const* d_in, const int* in_sizes, int n_in,
                              void* d_out, int out_size, void* d_ws, size_t ws_size,
                              hipStream_t stream) {
  const float* sino   = (const float*)d_in[0];
  const float* angles = (const float*)d_in[1];
  float* out = (float*)d_out;

  size_t need = (size_t)SINO_N * sizeof(H8);   // 31.5 MB
  if (ws_size >= need) {
    H8* sino_h = (H8*)d_ws;
    sino_to_h<<<SINO_N / 256, 256, 0, stream>>>(sino, sino_h);
    backproject_h<<<(NVOX / 2) / 256, 256, 0, stream>>>(sino_h, angles, out);
  } else {
    backproject_direct<<<NVOX / 256, 256, 0, stream>>>(sino, angles, out);
  }
}